// Round 10
// baseline (191.907 us; speedup 1.0000x reference)
//
#include <hip/hip_runtime.h>
#include <math.h>

// Problem constants
#define DD    2048
#define EE    64
#define NTOK  8192
#define KS    2                 // k-split
#define KRANGE (DD / KS)        // 1024 k per gemm block
#define KC    32                // k per macro (= one MFMA K)
#define NM    (KRANGE / KC)     // 32 macros
#define MT    32                // tokens per gemm block

#define KPAD  2056              // Bt row stride (bf16 elems), 16B-aligned rows

// Output layout (all read back as float32 by harness):
#define PROB_OFF 0
#define IDX_OFF  524288
#define MASK_OFF 540672
#define MASK_K_STRIDE (NTOK * EE)
// Bt (split/transposed w) scratch lives in d_out's mask region: the epilogue
// fully overwrites that region afterwards (stream-ordered), so it's free.
#define BT_FLOAT_OFF 540672

#define GAP_THRESH 1e-3f        // ~50x the worst-case 3xbf16 z-error (R9-proven)

typedef float f32x4 __attribute__((ext_vector_type(4)));
typedef short s16x8 __attribute__((ext_vector_type(8)));
typedef short s16x4 __attribute__((ext_vector_type(4)));

// Exact split: x = hi + lo with hi = truncate-to-bf16(x), lo = bf16(x - hi).
// Dropped term lo*lo' ~ 2^-16 relative.
__device__ __forceinline__ void split_bf16(float x, short& h, short& l) {
  const unsigned u = __float_as_uint(x);
  h = (short)(u >> 16);
  const float r = x - __uint_as_float(u & 0xffff0000u);
  l = (short)(__float_as_uint(r) >> 16);
}

// ---------------------------------------------------------------------------
// Kernel 0: split+transpose w into Bt[h:128 rows][l:128 rows], [n][k] bf16
// row-major, stride KPAD. 1 MB, written once into d_out scratch.
// ---------------------------------------------------------------------------
__global__ __launch_bounds__(256) void wt_kernel(
    const float* __restrict__ wg, const float* __restrict__ wn,
    unsigned short* __restrict__ bt)
{
  const int n  = blockIdx.x;              // 0..127
  const float* __restrict__ w = (n < EE) ? (wg + n) : (wn + (n - EE));
  const int k0 = threadIdx.x * 8;

  short h[8], l[8];
#pragma unroll
  for (int j = 0; j < 8; ++j)
    split_bf16(w[(size_t)(k0 + j) * EE], h[j], l[j]);

  s16x8 vh = {h[0], h[1], h[2], h[3], h[4], h[5], h[6], h[7]};
  s16x8 vl = {l[0], l[1], l[2], l[3], l[4], l[5], l[6], l[7]};
  *reinterpret_cast<s16x8*>(bt + (size_t)n * KPAD + k0)         = vh;
  *reinterpret_cast<s16x8*>(bt + (size_t)(128 + n) * KPAD + k0) = vl;
}

// ---------------------------------------------------------------------------
// Kernel 1: MFMA GEMM (3xBF16 exact-split). Unchanged from R9 (proven fast).
// ---------------------------------------------------------------------------
__global__ __launch_bounds__(256) void router_gemm(
    const float* __restrict__ x,           // [NTOK][DD]
    const unsigned short* __restrict__ bt, // [256][KPAD] (h rows, then l rows)
    float* __restrict__ part)              // [NTOK][KS][2*EE]
{
  __shared__ unsigned short lds[12800];    // 25600 B
  const int AH = 0, AL = 1280, BH = 2560, BL = 7680;   // bf16-elem offsets

  const int tid  = threadIdx.x;
  const int wid  = tid >> 6;
  const int lane = tid & 63;
  const int quad = lane >> 4;
  const int l15  = lane & 15;
  const int wn0  = wid * 32;               // this wave's n-quarter

  const int tok0   = blockIdx.x * MT;
  const int ks     = blockIdx.y;
  const int k0base = ks * KRANGE;

  // staging roles
  const int ar  = tid >> 3;                // A row 0..31
  const int akq = (tid & 7) * 4;           // A k-offset (float4)
  const int bn  = tid >> 1;                // B row 0..127
  const int bh2 = (tid & 1) * 16;          // B k-half (16 bf16)

  const float* __restrict__ xsrc = x + (size_t)(tok0 + ar) * DD + k0base + akq;
  const unsigned short* __restrict__ bts_h = bt + (size_t)bn * KPAD + k0base + bh2;
  const unsigned short* __restrict__ bts_l = bt + (size_t)(128 + bn) * KPAD + k0base + bh2;

  f32x4 acc[2][2];
#pragma unroll
  for (int mt = 0; mt < 2; ++mt)
#pragma unroll
    for (int nt = 0; nt < 2; ++nt) acc[mt][nt] = (f32x4){0.f, 0.f, 0.f, 0.f};

  // prefetch macro 0
  float4 pa = *reinterpret_cast<const float4*>(xsrc);
  s16x8 pb0 = *reinterpret_cast<const s16x8*>(bts_h);
  s16x8 pb1 = *reinterpret_cast<const s16x8*>(bts_h + 8);
  s16x8 pb2 = *reinterpret_cast<const s16x8*>(bts_l);
  s16x8 pb3 = *reinterpret_cast<const s16x8*>(bts_l + 8);

  for (int m = 0; m < NM; ++m) {
    // ---- write staged macro m into LDS ----
    short h0, h1, h2, h3, l0, l1, l2, l3;
    split_bf16(pa.x, h0, l0); split_bf16(pa.y, h1, l1);
    split_bf16(pa.z, h2, l2); split_bf16(pa.w, h3, l3);
    s16x4 vh = {h0, h1, h2, h3};
    s16x4 vl = {l0, l1, l2, l3};
    *reinterpret_cast<s16x4*>(&lds[AH + ar * 40 + akq]) = vh;
    *reinterpret_cast<s16x4*>(&lds[AL + ar * 40 + akq]) = vl;
    *reinterpret_cast<s16x8*>(&lds[BH + bn * 40 + bh2])     = pb0;
    *reinterpret_cast<s16x8*>(&lds[BH + bn * 40 + bh2 + 8]) = pb1;
    *reinterpret_cast<s16x8*>(&lds[BL + bn * 40 + bh2])     = pb2;
    *reinterpret_cast<s16x8*>(&lds[BL + bn * 40 + bh2 + 8]) = pb3;

    // ---- prefetch macro m+1 (in flight across this macro's compute) ----
    if (m + 1 < NM) {
      const int ko = (m + 1) * KC;
      pa  = *reinterpret_cast<const float4*>(xsrc + ko);
      pb0 = *reinterpret_cast<const s16x8*>(bts_h + ko);
      pb1 = *reinterpret_cast<const s16x8*>(bts_h + ko + 8);
      pb2 = *reinterpret_cast<const s16x8*>(bts_l + ko);
      pb3 = *reinterpret_cast<const s16x8*>(bts_l + ko + 8);
    }
    __builtin_amdgcn_sched_barrier(0);   // don't sink the prefetch
    __syncthreads();                     // tile m visible

    // ---- compute macro m (LDS-only operands) ----
    s16x8 af[2], al[2], bf[2], bl[2];
#pragma unroll
    for (int mt = 0; mt < 2; ++mt) {
      const int row = mt * 16 + l15;
      af[mt] = *reinterpret_cast<const s16x8*>(&lds[AH + row * 40 + quad * 8]);
      al[mt] = *reinterpret_cast<const s16x8*>(&lds[AL + row * 40 + quad * 8]);
    }
#pragma unroll
    for (int nt = 0; nt < 2; ++nt) {
      const int row = wn0 + nt * 16 + l15;
      bf[nt] = *reinterpret_cast<const s16x8*>(&lds[BH + row * 40 + quad * 8]);
      bl[nt] = *reinterpret_cast<const s16x8*>(&lds[BL + row * 40 + quad * 8]);
    }
#pragma unroll
    for (int mt = 0; mt < 2; ++mt)
#pragma unroll
      for (int nt = 0; nt < 2; ++nt) {
        acc[mt][nt] = __builtin_amdgcn_mfma_f32_16x16x32_bf16(af[mt], bf[nt], acc[mt][nt], 0, 0, 0);
        acc[mt][nt] = __builtin_amdgcn_mfma_f32_16x16x32_bf16(af[mt], bl[nt], acc[mt][nt], 0, 0, 0);
        acc[mt][nt] = __builtin_amdgcn_mfma_f32_16x16x32_bf16(al[mt], bf[nt], acc[mt][nt], 0, 0, 0);
      }
    __syncthreads();                     // readers done before next write
  }

  // ---- store fp32 partials [t][KS][128]; C: col=lane&15, row=quad*4+reg ----
#pragma unroll
  for (int mt = 0; mt < 2; ++mt)
#pragma unroll
    for (int nt = 0; nt < 2; ++nt) {
      const int col = wn0 + nt * 16 + l15;
#pragma unroll
      for (int r = 0; r < 4; ++r) {
        const int t = tok0 + mt * 16 + quad * 4 + r;
        part[((size_t)t * KS + ks) * (2 * EE) + col] = acc[mt][nt][r];
      }
    }
}

// ---------------------------------------------------------------------------
// Kernel 2: epilogue (4 tokens/block). Fast path: sum KS partials, softplus,
// top-2/top-3 butterflies, gap check. Near-tie tokens are recomputed by the
// WHOLE BLOCK cooperatively (R9's per-wave serial loop was a 60 us straggler):
// x row staged to LDS, thread (col 0..127, khalf 0..1) does a 1024-k partial
// dot (LDS-broadcast x, coalesced w), LDS-reduce, owner wave redoes top-2.
// ---------------------------------------------------------------------------
__global__ __launch_bounds__(256) void router_epilogue(
    const float* __restrict__ part,      // [NTOK][KS][2*EE]
    const float* __restrict__ noise_eps, // [NTOK][EE]
    const float* __restrict__ x,         // [NTOK][DD]
    const float* __restrict__ wg,        // [DD][EE]
    const float* __restrict__ wn,        // [DD][EE]
    float* __restrict__ out)
{
  __shared__ float xs[DD];       // 8 KB staged x row (fixup)
  __shared__ float zred[128];    // khalf=1 partials
  __shared__ float zfix[128];    // exact logits
  __shared__ int   flagmask;

  const int tid  = threadIdx.x;
  const int wid  = tid >> 6;
  const int lane = tid & 63;
  const int t0   = blockIdx.x * 4;
  const int t    = t0 + wid;

  if (tid == 0) flagmask = 0;

  const float* p = part + (size_t)t * KS * (2 * EE);
  float g    = p[lane]      + p[128 + lane];
  float nraw = p[EE + lane] + p[128 + EE + lane];
  const float ep = noise_eps[(size_t)t * EE + lane];

  float sp = fmaxf(nraw, 0.0f) + log1pf(expf(-fabsf(nraw)));
  float z  = fmaf(sp, ep, g);

  // top-1 / top-2 butterflies (all lanes converge)
  float v1 = z; int i1 = lane;
#pragma unroll
  for (int off = 32; off >= 1; off >>= 1) {
    const float ov = __shfl_xor(v1, off, 64);
    const int   oi = __shfl_xor(i1, off, 64);
    if (ov > v1 || (ov == v1 && oi < i1)) { v1 = ov; i1 = oi; }
  }
  float v2 = (lane == i1) ? -INFINITY : z; int i2 = lane;
#pragma unroll
  for (int off = 32; off >= 1; off >>= 1) {
    const float ov = __shfl_xor(v2, off, 64);
    const int   oi = __shfl_xor(i2, off, 64);
    if (ov > v2 || (ov == v2 && oi < i2)) { v2 = ov; i2 = oi; }
  }
  float v3 = (lane == i1 || lane == i2) ? -INFINITY : z;
#pragma unroll
  for (int off = 32; off >= 1; off >>= 1)
    v3 = fmaxf(v3, __shfl_xor(v3, off, 64));

  const bool bad = (v1 - v2 < GAP_THRESH) || (v2 - v3 < GAP_THRESH);
  __syncthreads();                       // flagmask init visible
  if (bad && lane == 0) atomicOr(&flagmask, 1 << wid);
  __syncthreads();

  int fm = flagmask;
  while (fm) {                           // block-uniform loop over flagged
    const int w  = __ffs(fm) - 1; fm &= fm - 1;
    const int tf = t0 + w;

    // stage x row (256 threads x 2 float4)
    const float4* xrow = reinterpret_cast<const float4*>(x + (size_t)tf * DD);
#pragma unroll
    for (int i = 0; i < DD / 4 / 256; ++i)
      reinterpret_cast<float4*>(xs)[tid + 256 * i] = xrow[tid + 256 * i];
    __syncthreads();

    // exact fp32 partial dot: col = output column, kh = k-half
    const int col = tid & 127;
    const int kh  = tid >> 7;
    const float* __restrict__ W = (col < EE) ? (wg + col) : (wn + (col - EE));
    const int kbeg = kh * (DD / 2);
    float a = 0.0f;
#pragma unroll 8
    for (int k = 0; k < DD / 2; ++k)
      a = fmaf(xs[kbeg + k], W[(size_t)(kbeg + k) * EE], a);
    if (kh == 1) zred[col] = a;
    __syncthreads();
    if (kh == 0) zfix[col] = a + zred[col];
    __syncthreads();

    if (wid == w) {                      // owner wave: redo top-2 exactly
      const float gf = zfix[lane];
      const float nf = zfix[EE + lane];
      const float spf = fmaxf(nf, 0.0f) + log1pf(expf(-fabsf(nf)));
      const float zf  = fmaf(spf, ep, gf);
      v1 = zf; i1 = lane;
#pragma unroll
      for (int off = 32; off >= 1; off >>= 1) {
        const float ov = __shfl_xor(v1, off, 64);
        const int   oi = __shfl_xor(i1, off, 64);
        if (ov > v1 || (ov == v1 && oi < i1)) { v1 = ov; i1 = oi; }
      }
      v2 = (lane == i1) ? -INFINITY : zf; i2 = lane;
#pragma unroll
      for (int off = 32; off >= 1; off >>= 1) {
        const float ov = __shfl_xor(v2, off, 64);
        const int   oi = __shfl_xor(i2, off, 64);
        if (ov > v2 || (ov == v2 && oi < i2)) { v2 = ov; i2 = oi; }
      }
    }
    __syncthreads();                     // xs reuse safe next iteration
  }

  const float e2 = expf(v2 - v1);
  const float denom = 1.0f + e2;
  const float p1 = 1.0f / denom;
  const float p2 = e2 / denom;

  out[PROB_OFF + (size_t)t * EE + lane] =
      (lane == i1) ? p1 : ((lane == i2) ? p2 : 0.0f);

  if (lane == 0) {
    out[IDX_OFF + t * 2 + 0] = (float)i1;
    out[IDX_OFF + t * 2 + 1] = (float)i2;
  }

  out[MASK_OFF + 0 * MASK_K_STRIDE + (size_t)t * EE + lane] = (lane == i1) ? 1.0f : 0.0f;
  out[MASK_OFF + 1 * MASK_K_STRIDE + (size_t)t * EE + lane] = (lane == i2) ? 1.0f : 0.0f;
}

// ---------------------------------------------------------------------------
extern "C" void kernel_launch(void* const* d_in, const int* in_sizes, int n_in,
                              void* d_out, int out_size, void* d_ws, size_t ws_size,
                              hipStream_t stream) {
  const float* x   = (const float*)d_in[0];
  const float* eps = (const float*)d_in[1];
  const float* wg  = (const float*)d_in[2];
  const float* wn  = (const float*)d_in[3];
  float* out = (float*)d_out;
  float* ws  = (float*)d_ws;   // KS * 4 MB = 8 MB fp32 partials

  unsigned short* bt = (unsigned short*)(out + BT_FLOAT_OFF);

  wt_kernel<<<dim3(128), dim3(256), 0, stream>>>(wg, wn, bt);
  router_gemm<<<dim3(NTOK / MT, KS), dim3(256), 0, stream>>>(x, bt, ws);
  router_epilogue<<<dim3(NTOK / 4), dim3(256), 0, stream>>>(ws, eps, x, wg, wn, out);
}